// Round 5
// baseline (1049.469 us; speedup 1.0000x reference)
//
#include <hip/hip_runtime.h>
#include <hip/hip_bf16.h>

// Sizes (fixed): B=64 T=128 HID=512 LOC_EMB=256 TIM_EMB=64 UID_EMB=128
// L_HIST=1024 G=4, K_x=320, K_attn=448, N_gates=1536, UID_SIZE=5000

typedef __attribute__((ext_vector_type(8))) short bf16x8;
typedef __attribute__((ext_vector_type(4))) float f32x4;
typedef __attribute__((ext_vector_type(4))) unsigned short u16x4;
typedef __attribute__((ext_vector_type(2))) unsigned long long u64x2;
typedef unsigned long long u64;

__device__ inline unsigned short f2bf(float x) {
  __hip_bfloat16 b = __float2bfloat16(x);
  return __builtin_bit_cast(unsigned short, b);
}

// ---------------- gather x = [emb_loc[loc], emb_tim[tim]] -> X[(t*64+b)][320] ----------------
__global__ void gather_x(const int* __restrict__ loc, const int* __restrict__ tim,
                         const float* __restrict__ eloc, const float* __restrict__ etim,
                         float* __restrict__ X) {
  int row = blockIdx.x;            // t*64 + b
  int t = row >> 6, b = row & 63;
  int tid = threadIdx.x;           // 64 threads
  float4* dst = (float4*)(X + (size_t)row * 320);
  int li = loc[b * 128 + t];
  dst[tid] = ((const float4*)(eloc + (size_t)li * 256))[tid];
  if (tid < 16) {
    int ti = tim[b * 128 + t];
    dst[64 + tid] = ((const float4*)(etim + (size_t)ti * 64))[tid];
  }
}

// ---------------- hist features: [loc(256) | tim(64) | uid_mean(128)] per (b, n) ----------------
__global__ void hist_feat(const int* __restrict__ hloc, const int* __restrict__ htim,
                          const int* __restrict__ huid,
                          const float* __restrict__ eloc, const float* __restrict__ etim,
                          const float* __restrict__ euid, float* __restrict__ histf) {
  int row = blockIdx.x;            // b*256 + n
  int b = row >> 8, n = row & 255;
  int tid = threadIdx.x;           // 64 threads
  int base = b * 1024 + (n << 2);
  float4* dst = (float4*)(histf + (size_t)row * 448);
  {
    int li = hloc[base];
    dst[tid] = ((const float4*)(eloc + (size_t)li * 256))[tid];
  }
  if (tid < 16) {
    int ti = htim[base];
    dst[64 + tid] = ((const float4*)(etim + (size_t)ti * 64))[tid];
  }
  if (tid < 32) {
    const float4* u0 = (const float4*)(euid + (size_t)huid[base + 0] * 128);
    const float4* u1 = (const float4*)(euid + (size_t)huid[base + 1] * 128);
    const float4* u2 = (const float4*)(euid + (size_t)huid[base + 2] * 128);
    const float4* u3 = (const float4*)(euid + (size_t)huid[base + 3] * 128);
    float4 v0 = u0[tid], v1 = u1[tid], v2 = u2[tid], v3 = u3[tid];
    float4 o;
    o.x = 0.25f * (v0.x + v1.x + v2.x + v3.x);
    o.y = 0.25f * (v0.y + v1.y + v2.y + v3.y);
    o.z = 0.25f * (v0.z + v1.z + v2.z + v3.z);
    o.w = 0.25f * (v0.w + v1.w + v2.w + v3.w);
    dst[80 + tid] = o;
  }
}

// ---------------- fp32 tiled GEMM: C[m][n] = act(sum_k A[m][k]*B[n][k] + bias[n]) ----------------
template<bool TANH>
__global__ __launch_bounds__(256)
void gemm_bt(const float* __restrict__ A, const float* __restrict__ Bm,
             const float* __restrict__ bias, float* __restrict__ C,
             int M, int N, int K) {
  constexpr int BM = 128, BN = 128, BK = 16;
  __shared__ float As[BK][BM + 4];
  __shared__ float Bs[BK][BN + 4];
  const int tid = threadIdx.x;
  const int bm = blockIdx.y * BM, bn = blockIdx.x * BN;
  const int tm = (tid >> 4) << 3, tn = (tid & 15) << 3;
  const int lr = tid >> 2;
  const int lc = (tid & 3) << 2;
  const float* Ap0 = A + (size_t)(bm + lr) * K + lc;
  const float* Ap1 = A + (size_t)(bm + 64 + lr) * K + lc;
  const float* Bp0 = Bm + (size_t)(bn + lr) * K + lc;
  const float* Bp1 = Bm + (size_t)(bn + 64 + lr) * K + lc;
  float acc[8][8] = {};
  for (int k0 = 0; k0 < K; k0 += BK) {
    float4 a0 = *(const float4*)(Ap0 + k0);
    float4 a1 = *(const float4*)(Ap1 + k0);
    float4 b0 = *(const float4*)(Bp0 + k0);
    float4 b1 = *(const float4*)(Bp1 + k0);
    As[lc + 0][lr] = a0.x; As[lc + 1][lr] = a0.y; As[lc + 2][lr] = a0.z; As[lc + 3][lr] = a0.w;
    As[lc + 0][64 + lr] = a1.x; As[lc + 1][64 + lr] = a1.y; As[lc + 2][64 + lr] = a1.z; As[lc + 3][64 + lr] = a1.w;
    Bs[lc + 0][lr] = b0.x; Bs[lc + 1][lr] = b0.y; Bs[lc + 2][lr] = b0.z; Bs[lc + 3][lr] = b0.w;
    Bs[lc + 0][64 + lr] = b1.x; Bs[lc + 1][64 + lr] = b1.y; Bs[lc + 2][64 + lr] = b1.z; Bs[lc + 3][64 + lr] = b1.w;
    __syncthreads();
#pragma unroll
    for (int kk = 0; kk < BK; ++kk) {
      float a[8], bv[8];
      *(float4*)&a[0]  = *(const float4*)&As[kk][tm];
      *(float4*)&a[4]  = *(const float4*)&As[kk][tm + 4];
      *(float4*)&bv[0] = *(const float4*)&Bs[kk][tn];
      *(float4*)&bv[4] = *(const float4*)&Bs[kk][tn + 4];
#pragma unroll
      for (int i = 0; i < 8; ++i)
#pragma unroll
        for (int j = 0; j < 8; ++j)
          acc[i][j] += a[i] * bv[j];
    }
    __syncthreads();
  }
#pragma unroll
  for (int i = 0; i < 8; ++i) {
    float* crow = C + (size_t)(bm + tm + i) * N + bn + tn;
#pragma unroll
    for (int j = 0; j < 8; ++j) {
      float v = acc[i][j] + bias[bn + tn + j];
      if (TANH) v = tanhf(v);
      crow[j] = v;
    }
  }
}

// ---------------- persistent GRU: all 128 steps in one kernel ----------------
// 64 blocks x 128 threads (2 independent waves, no intra-block sync).
// wave = virtual producer p = c*2 + tt, owns 16 j-rows [32c + 16tt, +16) for
// batches [16g, 16g+16), g = bid&3, c = bid>>2.
// Weights: 3 gates x 16 ks x bf16x8 = 192 VGPRs, preloaded once (loop-invariant).
// h exchange: L3-direct relaxed agent atomics, no fences:
//   producer: 8B atomic h store -> s_waitcnt vmcnt(0) -> relaxed flag store
//   consumer: relaxed 32-flag poll -> 8B atomic h loads (fresh from L3)
__global__ __launch_bounds__(128)
void gru_persist(const float* __restrict__ gx, const float* __restrict__ W_hh,
                 const float* __restrict__ b_hh, const int* __restrict__ lens,
                 short* __restrict__ h_bf, float* __restrict__ lastb,
                 unsigned int* __restrict__ flags) {
  const int tid = threadIdx.x;
  const int lane = tid & 63, tt = tid >> 6;
  const int bid = blockIdx.x;
  const int c = bid >> 2, grp = bid & 3;
  const int j0 = (c << 5) + (tt << 4);   // this wave's 16 j-rows
  const int b0 = grp << 4;               // 16 batches
  const int m16 = lane & 15, g4 = lane >> 4;

  // ---- preload weight fragments into registers (once) ----
  // A-frag(ks): lane(m16,g4) holds W[j0+m16][ks*32 + g4*8 .. +8]
  bf16x8 wr_[16], wz_[16], wn_[16];
  {
    const float* wr = W_hh + (size_t)(j0 + m16) * 512 + (g4 << 3);
    const float* wz = wr + 512 * 512;
    const float* wn = wr + 1024 * 512;
#pragma unroll
    for (int ks = 0; ks < 16; ++ks) {
      float4 a, b; bf16x8 w;
      a = *(const float4*)(wr + ks * 32); b = *(const float4*)(wr + ks * 32 + 4);
      w[0]=(short)f2bf(a.x); w[1]=(short)f2bf(a.y); w[2]=(short)f2bf(a.z); w[3]=(short)f2bf(a.w);
      w[4]=(short)f2bf(b.x); w[5]=(short)f2bf(b.y); w[6]=(short)f2bf(b.z); w[7]=(short)f2bf(b.w);
      wr_[ks] = w;
      a = *(const float4*)(wz + ks * 32); b = *(const float4*)(wz + ks * 32 + 4);
      w[0]=(short)f2bf(a.x); w[1]=(short)f2bf(a.y); w[2]=(short)f2bf(a.z); w[3]=(short)f2bf(a.w);
      w[4]=(short)f2bf(b.x); w[5]=(short)f2bf(b.y); w[6]=(short)f2bf(b.z); w[7]=(short)f2bf(b.w);
      wz_[ks] = w;
      a = *(const float4*)(wn + ks * 32); b = *(const float4*)(wn + ks * 32 + 4);
      w[0]=(short)f2bf(a.x); w[1]=(short)f2bf(a.y); w[2]=(short)f2bf(a.z); w[3]=(short)f2bf(a.w);
      w[4]=(short)f2bf(b.x); w[5]=(short)f2bf(b.y); w[6]=(short)f2bf(b.z); w[7]=(short)f2bf(b.w);
      wn_[ks] = w;
    }
  }

  // ---- per-lane constants ----
  const int bcol = b0 + m16;             // this lane's batch (C-col)
  const int jr = j0 + (g4 << 2);         // this lane's 4 output j-rows (C-rows)
  const f32x4 bhr = *(const f32x4*)&b_hh[jr];
  const f32x4 bhz = *(const f32x4*)&b_hh[512 + jr];
  const f32x4 bhn = *(const f32x4*)&b_hh[1024 + jr];
  const int lenb = lens[bcol];
  f32x4 hprev = {0.f, 0.f, 0.f, 0.f};

  unsigned int* gflags = flags + (grp << 9);       // 32 flags x 16 dwords (64B) apart
  unsigned int* ownflag = gflags + (((c << 1) + tt) << 4);

  for (int t = 0; t < 128; ++t) {
    f32x4 ar = {0.f, 0.f, 0.f, 0.f}, az = ar, an = ar;
    f32x4 gr, gz, gn;
    if (t) {
      // wait: all 32 producer-waves of this group finished step t-1 (relaxed poll)
      unsigned tgt = (unsigned)t;
      while (true) {
        unsigned f = tgt;
        if (lane < 32)
          f = __hip_atomic_load(gflags + (lane << 4), __ATOMIC_RELAXED, __HIP_MEMORY_SCOPE_AGENT);
        if (__all((int)(f >= tgt))) break;
      }
      asm volatile("" ::: "memory");   // compile-time ordering only

      // h loads first (L3-direct), then gx (HBM) - MFMA waits only on h
      const u64* hp = (const u64*)(h_bf + ((t & 1) << 15) + (size_t)bcol * 512 + (g4 << 3));
      u64 hu[32];
#pragma unroll
      for (int ks = 0; ks < 16; ++ks) {
        hu[2 * ks]     = __hip_atomic_load(hp + ks * 8,     __ATOMIC_RELAXED, __HIP_MEMORY_SCOPE_AGENT);
        hu[2 * ks + 1] = __hip_atomic_load(hp + ks * 8 + 1, __ATOMIC_RELAXED, __HIP_MEMORY_SCOPE_AGENT);
      }
      const float* gxb = gx + ((size_t)t * 64 + bcol) * 1536;
      gr = *(const f32x4*)(gxb + jr);
      gz = *(const f32x4*)(gxb + 512 + jr);
      gn = *(const f32x4*)(gxb + 1024 + jr);
#define GRU_MFMA(ks)                                                                \
      {                                                                             \
        u64x2 p; p[0] = hu[2 * (ks)]; p[1] = hu[2 * (ks) + 1];                      \
        bf16x8 hf = __builtin_bit_cast(bf16x8, p);                                  \
        ar = __builtin_amdgcn_mfma_f32_16x16x32_bf16(wr_[ks], hf, ar, 0, 0, 0);     \
        az = __builtin_amdgcn_mfma_f32_16x16x32_bf16(wz_[ks], hf, az, 0, 0, 0);     \
        an = __builtin_amdgcn_mfma_f32_16x16x32_bf16(wn_[ks], hf, an, 0, 0, 0);     \
      }
      GRU_MFMA(0)  GRU_MFMA(1)  GRU_MFMA(2)  GRU_MFMA(3)
      GRU_MFMA(4)  GRU_MFMA(5)  GRU_MFMA(6)  GRU_MFMA(7)
      GRU_MFMA(8)  GRU_MFMA(9)  GRU_MFMA(10) GRU_MFMA(11)
      GRU_MFMA(12) GRU_MFMA(13) GRU_MFMA(14) GRU_MFMA(15)
#undef GRU_MFMA
    } else {
      const float* gxb = gx + (size_t)bcol * 1536;
      gr = *(const f32x4*)(gxb + jr);
      gz = *(const f32x4*)(gxb + 512 + jr);
      gn = *(const f32x4*)(gxb + 1024 + jr);
    }
    u16x4 hw;
#pragma unroll
    for (int q = 0; q < 4; ++q) {
      float r = 1.f / (1.f + __expf(-(gr[q] + ar[q] + bhr[q])));
      float z = 1.f / (1.f + __expf(-(gz[q] + az[q] + bhz[q])));
      float xn = gn[q] + r * (an[q] + bhn[q]);
      float n = 1.f - 2.f / (__expf(2.f * xn) + 1.f);
      float hv = (1.f - z) * n + z * hprev[q];
      hprev[q] = hv;
      hw[q] = f2bf(hv);
    }
    __hip_atomic_store((u64*)(h_bf + ((~t & 1) << 15) + (size_t)bcol * 512 + jr),
                       __builtin_bit_cast(u64, hw),
                       __ATOMIC_RELAXED, __HIP_MEMORY_SCOPE_AGENT);
    if (t == lenb - 1) {
      *(f32x4*)(lastb + (size_t)bcol * 512 + jr) = hprev;
    }
    if (t < 127) {
      asm volatile("s_waitcnt vmcnt(0)" ::: "memory");   // h store acked at coherence point
      if (lane == 0)
        __hip_atomic_store(ownflag, (unsigned)(t + 1), __ATOMIC_RELAXED, __HIP_MEMORY_SCOPE_AGENT);
    }
  }
}

// ---------------- attention: energies, softmax, context (one block per b) ----------------
__global__ __launch_bounds__(256)
void attn_ctx(const float* __restrict__ histt, const float* __restrict__ last,
              float* __restrict__ ctx) {
  int b = blockIdx.x, tid = threadIdx.x;
  __shared__ float ls[512];
  __shared__ float w[256];
  __shared__ float red[256];
  ((float2*)ls)[tid] = ((const float2*)(last + (size_t)b * 512))[tid];
  __syncthreads();
  const float* hb = histt + (size_t)b * 256 * 512;
  const float* hrow = hb + (size_t)tid * 512;
  float acc = 0.f;
  for (int k = 0; k < 512; k += 4) {
    float4 h4 = *(const float4*)(hrow + k);
    acc += ls[k] * h4.x + ls[k + 1] * h4.y + ls[k + 2] * h4.z + ls[k + 3] * h4.w;
  }
  red[tid] = acc;
  __syncthreads();
  for (int s = 128; s; s >>= 1) {
    if (tid < s) red[tid] = fmaxf(red[tid], red[tid + s]);
    __syncthreads();
  }
  float m = red[0];
  __syncthreads();
  float ex = expf(acc - m);
  w[tid] = ex; red[tid] = ex;
  __syncthreads();
  for (int s = 128; s; s >>= 1) {
    if (tid < s) red[tid] += red[tid + s];
    __syncthreads();
  }
  float inv = 1.f / red[0];
  float c0 = 0.f, c1 = 0.f;
  for (int n = 0; n < 256; ++n) {
    float wn = w[n];
    c0 += wn * hb[(size_t)n * 512 + tid];
    c1 += wn * hb[(size_t)n * 512 + tid + 256];
  }
  ctx[(size_t)b * 512 + tid]       = c0 * inv;
  ctx[(size_t)b * 512 + tid + 256] = c1 * inv;
}

// ---------------- final: y[b][u] = [last|ctx|last] . W_final[u] + b_final[u] ----------------
__global__ __launch_bounds__(256)
void final_gemm(const float* __restrict__ last, const float* __restrict__ ctx,
                const float* __restrict__ Wf, const float* __restrict__ bf,
                float* __restrict__ y) {
  __shared__ float s[64][129];
  const int tid = threadIdx.x;
  const int u0 = blockIdx.x << 3;
  const int ul = tid >> 6, b = tid & 63;
  float acc0 = 0.f, acc1 = 0.f;
  for (int kc = 0; kc < 12; ++kc) {
    __syncthreads();
    for (int i = tid; i < 2048; i += 256) {
      int rb = i >> 5, cc = (i & 31) << 2;
      int k = kc * 128 + cc;
      const float* src = (k < 512) ? (last + (size_t)rb * 512 + k)
                       : (k < 1024) ? (ctx + (size_t)rb * 512 + k - 512)
                                    : (last + (size_t)rb * 512 + k - 1024);
      float4 v = *(const float4*)src;
      s[rb][cc] = v.x; s[rb][cc + 1] = v.y; s[rb][cc + 2] = v.z; s[rb][cc + 3] = v.w;
    }
    __syncthreads();
#pragma unroll
    for (int uu = 0; uu < 2; ++uu) {
      int u = u0 + ul + uu * 4;
      const float* wrow = Wf + (size_t)u * 1536 + kc * 128;
      float a = 0.f;
#pragma unroll 8
      for (int c = 0; c < 128; c += 4) {
        float4 w4 = *(const float4*)(wrow + c);
        a += w4.x * s[b][c] + w4.y * s[b][c + 1] + w4.z * s[b][c + 2] + w4.w * s[b][c + 3];
      }
      if (uu == 0) acc0 += a; else acc1 += a;
    }
  }
  int u = u0 + ul;
  y[(size_t)b * 5000 + u]     = acc0 + bf[u];
  y[(size_t)b * 5000 + u + 4] = acc1 + bf[u + 4];
}

// ---------------- broadcast y (B,5000) -> out (B,T,5000) ----------------
__global__ void broadcast_y(const float* __restrict__ y, float* __restrict__ out) {
  int bt = blockIdx.x;
  const float4* src = (const float4*)(y + (size_t)(bt >> 7) * 5000);
  float4* dst = (float4*)(out + (size_t)bt * 5000);
  for (int i = threadIdx.x; i < 1250; i += 256) dst[i] = src[i];
}

extern "C" void kernel_launch(void* const* d_in, const int* in_sizes, int n_in,
                              void* d_out, int out_size, void* d_ws, size_t ws_size,
                              hipStream_t stream) {
  const int* loc  = (const int*)d_in[0];
  const int* tim  = (const int*)d_in[1];
  const int* lens = (const int*)d_in[2];
  const int* hloc = (const int*)d_in[3];
  const int* htim = (const int*)d_in[4];
  const int* huid = (const int*)d_in[5];
  // d_in[6] = group_size (constant 4, baked in)
  const float* eloc    = (const float*)d_in[7];
  const float* etim    = (const float*)d_in[8];
  const float* euid    = (const float*)d_in[9];
  const float* W_attn  = (const float*)d_in[10];
  const float* b_attn  = (const float*)d_in[11];
  const float* W_ih    = (const float*)d_in[12];
  const float* b_ih    = (const float*)d_in[13];
  const float* W_hh    = (const float*)d_in[14];
  const float* b_hh    = (const float*)d_in[15];
  const float* W_final = (const float*)d_in[16];
  const float* b_final = (const float*)d_in[17];
  float* out = (float*)d_out;
  char* ws = (char*)d_ws;

  // workspace layout (bytes)
  float* X     = (float*)(ws + 0ull);            // 8192*320*4   = 10,485,760
  float* gx    = (float*)(ws + 10485760ull);     // 8192*1536*4  = 50,331,648
  float* histf = (float*)(ws + 60817408ull);     // 16384*448*4  = 29,360,128
  float* histt = (float*)(ws + 90177536ull);     // 16384*512*4  = 33,554,432
  float* lastb = (float*)(ws + 123731968ull);    // 64*512*4
  float* ctx   = (float*)(ws + 123863040ull);    // 64*512*4
  float* yv    = (float*)(ws + 123994112ull);    // 64*5000*4 = 1,280,000
  short* h_bf  = (short*)(ws + 125274112ull);    // 2*64*512*2 = 131,072
  // flags reuse histf's space (histf fully consumed before GRU launches)
  unsigned int* flags = (unsigned int*)(ws + 60817408ull);   // 4 grp x 32 x 64B = 8192

  gather_x<<<8192, 64, 0, stream>>>(loc, tim, eloc, etim, X);
  gemm_bt<false><<<dim3(12, 64), 256, 0, stream>>>(X, W_ih, b_ih, gx, 8192, 1536, 320);
  hist_feat<<<16384, 64, 0, stream>>>(hloc, htim, huid, eloc, etim, euid, histf);
  gemm_bt<true><<<dim3(4, 128), 256, 0, stream>>>(histf, W_attn, b_attn, histt, 16384, 512, 448);

  hipMemsetAsync(flags, 0, 8192, stream);   // stream-ordered: after gemm<true> consumed histf
  gru_persist<<<64, 128, 0, stream>>>(gx, W_hh, b_hh, lens, h_bf, lastb, flags);

  attn_ctx<<<64, 256, 0, stream>>>(histt, lastb, ctx);
  final_gemm<<<625, 256, 0, stream>>>(lastb, ctx, W_final, b_final, yv);
  broadcast_y<<<8192, 256, 0, stream>>>(yv, out);
}

// Round 7
// 692.532 us; speedup vs baseline: 1.5154x; 1.5154x over previous
//
#include <hip/hip_runtime.h>
#include <hip/hip_bf16.h>

// Sizes (fixed): B=64 T=128 HID=512 LOC_EMB=256 TIM_EMB=64 UID_EMB=128
// L_HIST=1024 G=4, K_x=320, K_attn=448, N_gates=1536, UID_SIZE=5000

typedef __attribute__((ext_vector_type(8))) short bf16x8;
typedef __attribute__((ext_vector_type(4))) float f32x4;
typedef __attribute__((ext_vector_type(4))) unsigned short u16x4;
typedef __attribute__((ext_vector_type(2))) unsigned long long u64x2;
typedef unsigned long long u64;

__device__ inline unsigned short f2bf(float x) {
  __hip_bfloat16 b = __float2bfloat16(x);
  return __builtin_bit_cast(unsigned short, b);
}

// ---------------- gather x = [emb_loc[loc], emb_tim[tim]] -> X[(t*64+b)][320] ----------------
__global__ void gather_x(const int* __restrict__ loc, const int* __restrict__ tim,
                         const float* __restrict__ eloc, const float* __restrict__ etim,
                         float* __restrict__ X) {
  int row = blockIdx.x;            // t*64 + b
  int t = row >> 6, b = row & 63;
  int tid = threadIdx.x;           // 64 threads
  float4* dst = (float4*)(X + (size_t)row * 320);
  int li = loc[b * 128 + t];
  dst[tid] = ((const float4*)(eloc + (size_t)li * 256))[tid];
  if (tid < 16) {
    int ti = tim[b * 128 + t];
    dst[64 + tid] = ((const float4*)(etim + (size_t)ti * 64))[tid];
  }
}

// ---------------- hist features: [loc(256) | tim(64) | uid_mean(128)] per (b, n) ----------------
__global__ void hist_feat(const int* __restrict__ hloc, const int* __restrict__ htim,
                          const int* __restrict__ huid,
                          const float* __restrict__ eloc, const float* __restrict__ etim,
                          const float* __restrict__ euid, float* __restrict__ histf) {
  int row = blockIdx.x;            // b*256 + n
  int b = row >> 8, n = row & 255;
  int tid = threadIdx.x;           // 64 threads
  int base = b * 1024 + (n << 2);
  float4* dst = (float4*)(histf + (size_t)row * 448);
  {
    int li = hloc[base];
    dst[tid] = ((const float4*)(eloc + (size_t)li * 256))[tid];
  }
  if (tid < 16) {
    int ti = htim[base];
    dst[64 + tid] = ((const float4*)(etim + (size_t)ti * 64))[tid];
  }
  if (tid < 32) {
    const float4* u0 = (const float4*)(euid + (size_t)huid[base + 0] * 128);
    const float4* u1 = (const float4*)(euid + (size_t)huid[base + 1] * 128);
    const float4* u2 = (const float4*)(euid + (size_t)huid[base + 2] * 128);
    const float4* u3 = (const float4*)(euid + (size_t)huid[base + 3] * 128);
    float4 v0 = u0[tid], v1 = u1[tid], v2 = u2[tid], v3 = u3[tid];
    float4 o;
    o.x = 0.25f * (v0.x + v1.x + v2.x + v3.x);
    o.y = 0.25f * (v0.y + v1.y + v2.y + v3.y);
    o.z = 0.25f * (v0.z + v1.z + v2.z + v3.z);
    o.w = 0.25f * (v0.w + v1.w + v2.w + v3.w);
    dst[80 + tid] = o;
  }
}

// ---------------- bf16 MFMA GEMM: C[m][n] = act(sum_k A[m][k]*B[n][k] + bias[n]) ----------------
// BM=BN=128, BK=32, 256 threads = 4 waves (2x2), 64x64 per wave.
// fp32 inputs converted to bf16 in reg-staging into PADDED LDS rows
// (stride 40 shorts = 80 B; no swizzle -- max 2-way bank aliasing at dRow=8, free).
template<bool TANH>
__global__ __launch_bounds__(256)
void gemm_bf16(const float* __restrict__ A, const float* __restrict__ Bm,
               const float* __restrict__ bias, float* __restrict__ C,
               int M, int N, int K) {
  constexpr int LDR = 40;                 // padded row stride in shorts
  __shared__ short Asl[128 * LDR];
  __shared__ short Bsl[128 * LDR];
  const int tid = threadIdx.x;
  const int lane = tid & 63, wid = tid >> 6;
  const int wr = wid >> 1, wc = wid & 1;
  const int m16 = lane & 15, g4 = lane >> 4;
  const int bm = blockIdx.y * 128, bn = blockIdx.x * 128;
  const int srow = tid >> 1, shalf = tid & 1;    // staging row, 16-col half
  f32x4 acc[4][4] = {};
  for (int k0 = 0; k0 < K; k0 += 32) {
    // ---- stage A and B (fp32 -> bf16), 2 granules of 8 shorts per thread ----
    {
      const float* ap = A + (size_t)(bm + srow) * K + k0 + (shalf << 4);
      float4 f0 = ((const float4*)ap)[0], f1 = ((const float4*)ap)[1];
      float4 f2 = ((const float4*)ap)[2], f3 = ((const float4*)ap)[3];
      bf16x8 w0, w1;
      w0[0]=(short)f2bf(f0.x); w0[1]=(short)f2bf(f0.y); w0[2]=(short)f2bf(f0.z); w0[3]=(short)f2bf(f0.w);
      w0[4]=(short)f2bf(f1.x); w0[5]=(short)f2bf(f1.y); w0[6]=(short)f2bf(f1.z); w0[7]=(short)f2bf(f1.w);
      w1[0]=(short)f2bf(f2.x); w1[1]=(short)f2bf(f2.y); w1[2]=(short)f2bf(f2.z); w1[3]=(short)f2bf(f2.w);
      w1[4]=(short)f2bf(f3.x); w1[5]=(short)f2bf(f3.y); w1[6]=(short)f2bf(f3.z); w1[7]=(short)f2bf(f3.w);
      short* arow = Asl + srow * LDR + (shalf << 4);
      *(bf16x8*)(arow)     = w0;
      *(bf16x8*)(arow + 8) = w1;
      const float* bp = Bm + (size_t)(bn + srow) * K + k0 + (shalf << 4);
      f0 = ((const float4*)bp)[0]; f1 = ((const float4*)bp)[1];
      f2 = ((const float4*)bp)[2]; f3 = ((const float4*)bp)[3];
      w0[0]=(short)f2bf(f0.x); w0[1]=(short)f2bf(f0.y); w0[2]=(short)f2bf(f0.z); w0[3]=(short)f2bf(f0.w);
      w0[4]=(short)f2bf(f1.x); w0[5]=(short)f2bf(f1.y); w0[6]=(short)f2bf(f1.z); w0[7]=(short)f2bf(f1.w);
      w1[0]=(short)f2bf(f2.x); w1[1]=(short)f2bf(f2.y); w1[2]=(short)f2bf(f2.z); w1[3]=(short)f2bf(f2.w);
      w1[4]=(short)f2bf(f3.x); w1[5]=(short)f2bf(f3.y); w1[6]=(short)f2bf(f3.z); w1[7]=(short)f2bf(f3.w);
      short* brow = Bsl + srow * LDR + (shalf << 4);
      *(bf16x8*)(brow)     = w0;
      *(bf16x8*)(brow + 8) = w1;
    }
    __syncthreads();
    bf16x8 af[4], bfr[4];
#pragma unroll
    for (int i = 0; i < 4; ++i) {
      int ra = (wr << 6) + (i << 4) + m16;
      af[i]  = *(const bf16x8*)(Asl + ra * LDR + (g4 << 3));
      int rb = (wc << 6) + (i << 4) + m16;
      bfr[i] = *(const bf16x8*)(Bsl + rb * LDR + (g4 << 3));
    }
#pragma unroll
    for (int i = 0; i < 4; ++i)
#pragma unroll
      for (int j = 0; j < 4; ++j)
        acc[i][j] = __builtin_amdgcn_mfma_f32_16x16x32_bf16(af[i], bfr[j], acc[i][j], 0, 0, 0);
    __syncthreads();
  }
  // ---- epilogue: bias (+tanh), fp32 C ----
#pragma unroll
  for (int i = 0; i < 4; ++i) {
#pragma unroll
    for (int j = 0; j < 4; ++j) {
      int col = bn + (wc << 6) + (j << 4) + m16;
      float bv = bias[col];
#pragma unroll
      for (int q = 0; q < 4; ++q) {
        int row = bm + (wr << 6) + (i << 4) + (g4 << 2) + q;
        float v = acc[i][j][q] + bv;
        if (TANH) v = tanhf(v);
        C[(size_t)row * N + col] = v;
      }
    }
  }
}

// ---------------- persistent GRU: all 128 steps in one kernel ----------------
// 64 blocks x 128 threads (2 cooperating waves). block = (chunk c = bid>>2, group g = bid&3).
// Block owns j in [32c, 32c+32), wave tt owns 16 of them; batches [16g, 16g+16).
// W_hh slice in LDS as bf16 (96 KB), XOR-swizzled; wave tt touches only its 3 slabs.
// h exchange: L3-direct relaxed agent atomics, no fences:
//   producer: 8B atomic h stores -> s_waitcnt vmcnt(0) -> __syncthreads -> flag store (1/block)
//   consumer: relaxed 16-flag poll -> 8B atomic h loads (fresh from L3 by construction)
// gx loads issued BEFORE the poll so HBM latency hides under the wait.
__global__ __launch_bounds__(128)
void gru_persist(const float* __restrict__ gx, const float* __restrict__ W_hh,
                 const float* __restrict__ b_hh, const int* __restrict__ lens,
                 short* __restrict__ h_bf, float* __restrict__ lastb,
                 unsigned int* __restrict__ flags) {
  __shared__ short wlds[6 * 16 * 512];   // 6 slabs (3 gates x 2 waves) x 16x512 bf16 = 96 KB
  const int tid = threadIdx.x;
  const int lane = tid & 63, tt = tid >> 6;
  const int bid = blockIdx.x;
  const int c = bid >> 2, grp = bid & 3;
  const int j0 = (c << 5) + (tt << 4);   // this wave's 16 j-rows
  const int b0 = grp << 4;               // 16 batches
  const int m16 = lane & 15, g4 = lane >> 4;

  // ---- load this wave's weight slabs into LDS (once), fp32 -> bf16, swizzled ----
  for (int gi = 0; gi < 3; ++gi) {
    const float* wg = W_hh + (size_t)(gi * 512 + j0) * 512;
    short* slab = wlds + (((gi << 1) + tt) << 13);
    for (int r = 0; r < 16; ++r) {
      int k = lane << 3;
      const float4* src = (const float4*)(wg + (size_t)r * 512 + k);
      float4 f0 = src[0], f1 = src[1];
      bf16x8 w;
      w[0]=(short)f2bf(f0.x); w[1]=(short)f2bf(f0.y); w[2]=(short)f2bf(f0.z); w[3]=(short)f2bf(f0.w);
      w[4]=(short)f2bf(f1.x); w[5]=(short)f2bf(f1.y); w[6]=(short)f2bf(f1.z); w[7]=(short)f2bf(f1.w);
      int off = ((r << 9) + k) ^ ((r & 7) << 3);   // short units (row=512 shorts, safe XOR)
      *(bf16x8*)(slab + off) = w;
    }
  }
  __syncthreads();

  // ---- per-lane constants ----
  const int bcol = b0 + m16;             // this lane's batch (C-col)
  const int jr = j0 + (g4 << 2);         // this lane's 4 output j-rows (C-rows)
  const f32x4 bhr = *(const f32x4*)&b_hh[jr];
  const f32x4 bhz = *(const f32x4*)&b_hh[512 + jr];
  const f32x4 bhn = *(const f32x4*)&b_hh[1024 + jr];
  const int lenb = lens[bcol];
  f32x4 hprev = {0.f, 0.f, 0.f, 0.f};

  unsigned int* gflags = flags + (grp << 8);       // 16 flags x 16 dwords (64B) apart
  unsigned int* ownflag = gflags + (c << 4);

  for (int t = 0; t < 128; ++t) {
    // gx loads first: independent of h, latency hides under the flag wait
    const float* gxb = gx + ((size_t)t * 64 + bcol) * 1536;
    f32x4 gr = *(const f32x4*)(gxb + jr);
    f32x4 gz = *(const f32x4*)(gxb + 512 + jr);
    f32x4 gn = *(const f32x4*)(gxb + 1024 + jr);
    f32x4 ar = {0.f, 0.f, 0.f, 0.f}, az = ar, an = ar;
    if (t) {
      // wait: all 16 chunk-blocks of this group finished step t-1 (relaxed poll)
      unsigned tgt = (unsigned)t;
      while (true) {
        unsigned f = tgt;
        if (lane < 16)
          f = __hip_atomic_load(gflags + (lane << 4), __ATOMIC_RELAXED, __HIP_MEMORY_SCOPE_AGENT);
        if (__all((int)(f >= tgt))) break;
      }
      asm volatile("" ::: "memory");   // compile-time ordering only

      // h loads: L3-direct atomics, fresh by construction (flag stored after vmcnt(0))
      const u64* hp = (const u64*)(h_bf + ((t & 1) << 15) + (size_t)bcol * 512 + (g4 << 3));
      u64 hu[32];
#pragma unroll
      for (int ks = 0; ks < 16; ++ks) {
        hu[2 * ks]     = __hip_atomic_load(hp + ks * 8,     __ATOMIC_RELAXED, __HIP_MEMORY_SCOPE_AGENT);
        hu[2 * ks + 1] = __hip_atomic_load(hp + ks * 8 + 1, __ATOMIC_RELAXED, __HIP_MEMORY_SCOPE_AGENT);
      }
#define GRU_MFMA(ks)                                                                 \
      {                                                                              \
        u64x2 p; p[0] = hu[2 * (ks)]; p[1] = hu[2 * (ks) + 1];                       \
        bf16x8 hf = __builtin_bit_cast(bf16x8, p);                                   \
        int off = ((m16 << 9) + ((ks) << 5) + (g4 << 3)) ^ ((m16 & 7) << 3);         \
        ar = __builtin_amdgcn_mfma_f32_16x16x32_bf16(*(const bf16x8*)(wlds + ((0 + tt) << 13) + off), hf, ar, 0, 0, 0); \
        az = __builtin_amdgcn_mfma_f32_16x16x32_bf16(*(const bf16x8*)(wlds + ((2 + tt) << 13) + off), hf, az, 0, 0, 0); \
        an = __builtin_amdgcn_mfma_f32_16x16x32_bf16(*(const bf16x8*)(wlds + ((4 + tt) << 13) + off), hf, an, 0, 0, 0); \
      }
      GRU_MFMA(0)  GRU_MFMA(1)  GRU_MFMA(2)  GRU_MFMA(3)
      GRU_MFMA(4)  GRU_MFMA(5)  GRU_MFMA(6)  GRU_MFMA(7)
      GRU_MFMA(8)  GRU_MFMA(9)  GRU_MFMA(10) GRU_MFMA(11)
      GRU_MFMA(12) GRU_MFMA(13) GRU_MFMA(14) GRU_MFMA(15)
#undef GRU_MFMA
    }
    u16x4 hw;
#pragma unroll
    for (int q = 0; q < 4; ++q) {
      float r = 1.f / (1.f + __expf(-(gr[q] + ar[q] + bhr[q])));
      float z = 1.f / (1.f + __expf(-(gz[q] + az[q] + bhz[q])));
      float xn = gn[q] + r * (an[q] + bhn[q]);
      float n = 1.f - 2.f / (__expf(2.f * xn) + 1.f);
      float hv = (1.f - z) * n + z * hprev[q];
      hprev[q] = hv;
      hw[q] = f2bf(hv);
    }
    __hip_atomic_store((u64*)(h_bf + ((~t & 1) << 15) + (size_t)bcol * 512 + jr),
                       __builtin_bit_cast(u64, hw),
                       __ATOMIC_RELAXED, __HIP_MEMORY_SCOPE_AGENT);
    if (t == lenb - 1) {
      *(f32x4*)(lastb + (size_t)bcol * 512 + jr) = hprev;
    }
    if (t < 127) {
      asm volatile("s_waitcnt vmcnt(0)" ::: "memory");   // this wave's h stores acked at L3
      __syncthreads();                                   // join both waves
      if (tid == 0)
        __hip_atomic_store(ownflag, (unsigned)(t + 1), __ATOMIC_RELAXED, __HIP_MEMORY_SCOPE_AGENT);
    }
  }
}

// ---------------- attention: energies, softmax, context (one block per b) ----------------
__global__ __launch_bounds__(256)
void attn_ctx(const float* __restrict__ histt, const float* __restrict__ last,
              float* __restrict__ ctx) {
  int b = blockIdx.x, tid = threadIdx.x;
  __shared__ float ls[512];
  __shared__ float w[256];
  __shared__ float red[256];
  ((float2*)ls)[tid] = ((const float2*)(last + (size_t)b * 512))[tid];
  __syncthreads();
  const float* hb = histt + (size_t)b * 256 * 512;
  const float* hrow = hb + (size_t)tid * 512;
  float acc = 0.f;
  for (int k = 0; k < 512; k += 4) {
    float4 h4 = *(const float4*)(hrow + k);
    acc += ls[k] * h4.x + ls[k + 1] * h4.y + ls[k + 2] * h4.z + ls[k + 3] * h4.w;
  }
  red[tid] = acc;
  __syncthreads();
  for (int s = 128; s; s >>= 1) {
    if (tid < s) red[tid] = fmaxf(red[tid], red[tid + s]);
    __syncthreads();
  }
  float m = red[0];
  __syncthreads();
  float ex = expf(acc - m);
  w[tid] = ex; red[tid] = ex;
  __syncthreads();
  for (int s = 128; s; s >>= 1) {
    if (tid < s) red[tid] += red[tid + s];
    __syncthreads();
  }
  float inv = 1.f / red[0];
  float c0 = 0.f, c1 = 0.f;
  for (int n = 0; n < 256; ++n) {
    float wn = w[n];
    c0 += wn * hb[(size_t)n * 512 + tid];
    c1 += wn * hb[(size_t)n * 512 + tid + 256];
  }
  ctx[(size_t)b * 512 + tid]       = c0 * inv;
  ctx[(size_t)b * 512 + tid + 256] = c1 * inv;
}

// ---------------- final: y[b][u] = [last|ctx|last] . W_final[u] + b_final[u] ----------------
__global__ __launch_bounds__(256)
void final_gemm(const float* __restrict__ last, const float* __restrict__ ctx,
                const float* __restrict__ Wf, const float* __restrict__ bf,
                float* __restrict__ y) {
  __shared__ float s[64][129];
  const int tid = threadIdx.x;
  const int u0 = blockIdx.x << 3;
  const int ul = tid >> 6, b = tid & 63;
  float acc0 = 0.f, acc1 = 0.f;
  for (int kc = 0; kc < 12; ++kc) {
    __syncthreads();
    for (int i = tid; i < 2048; i += 256) {
      int rb = i >> 5, cc = (i & 31) << 2;
      int k = kc * 128 + cc;
      const float* src = (k < 512) ? (last + (size_t)rb * 512 + k)
                       : (k < 1024) ? (ctx + (size_t)rb * 512 + k - 512)
                                    : (last + (size_t)rb * 512 + k - 1024);
      float4 v = *(const float4*)src;
      s[rb][cc] = v.x; s[rb][cc + 1] = v.y; s[rb][cc + 2] = v.z; s[rb][cc + 3] = v.w;
    }
    __syncthreads();
#pragma unroll
    for (int uu = 0; uu < 2; ++uu) {
      int u = u0 + ul + uu * 4;
      const float* wrow = Wf + (size_t)u * 1536 + kc * 128;
      float a = 0.f;
#pragma unroll 8
      for (int c = 0; c < 128; c += 4) {
        float4 w4 = *(const float4*)(wrow + c);
        a += w4.x * s[b][c] + w4.y * s[b][c + 1] + w4.z * s[b][c + 2] + w4.w * s[b][c + 3];
      }
      if (uu == 0) acc0 += a; else acc1 += a;
    }
  }
  int u = u0 + ul;
  y[(size_t)b * 5000 + u]     = acc0 + bf[u];
  y[(size_t)b * 5000 + u + 4] = acc1 + bf[u + 4];
}

// ---------------- broadcast y (B,5000) -> out (B,T,5000) ----------------
__global__ void broadcast_y(const float* __restrict__ y, float* __restrict__ out) {
  int bt = blockIdx.x;
  const float4* src = (const float4*)(y + (size_t)(bt >> 7) * 5000);
  float4* dst = (float4*)(out + (size_t)bt * 5000);
  for (int i = threadIdx.x; i < 1250; i += 256) dst[i] = src[i];
}

extern "C" void kernel_launch(void* const* d_in, const int* in_sizes, int n_in,
                              void* d_out, int out_size, void* d_ws, size_t ws_size,
                              hipStream_t stream) {
  const int* loc  = (const int*)d_in[0];
  const int* tim  = (const int*)d_in[1];
  const int* lens = (const int*)d_in[2];
  const int* hloc = (const int*)d_in[3];
  const int* htim = (const int*)d_in[4];
  const int* huid = (const int*)d_in[5];
  // d_in[6] = group_size (constant 4, baked in)
  const float* eloc    = (const float*)d_in[7];
  const float* etim    = (const float*)d_in[8];
  const float* euid    = (const float*)d_in[9];
  const float* W_attn  = (const float*)d_in[10];
  const float* b_attn  = (const float*)d_in[11];
  const float* W_ih    = (const float*)d_in[12];
  const float* b_ih    = (const float*)d_in[13];
  const float* W_hh    = (const float*)d_in[14];
  const float* b_hh    = (const float*)d_in[15];
  const float* W_final = (const float*)d_in[16];
  const float* b_final = (const float*)d_in[17];
  float* out = (float*)d_out;
  char* ws = (char*)d_ws;

  // workspace layout (bytes)
  float* X     = (float*)(ws + 0ull);            // 8192*320*4   = 10,485,760
  float* gx    = (float*)(ws + 10485760ull);     // 8192*1536*4  = 50,331,648
  float* histf = (float*)(ws + 60817408ull);     // 16384*448*4  = 29,360,128
  float* histt = (float*)(ws + 90177536ull);     // 16384*512*4  = 33,554,432
  float* lastb = (float*)(ws + 123731968ull);    // 64*512*4
  float* ctx   = (float*)(ws + 123863040ull);    // 64*512*4
  float* yv    = (float*)(ws + 123994112ull);    // 64*5000*4 = 1,280,000
  short* h_bf  = (short*)(ws + 125274112ull);    // 2*64*512*2 = 131,072
  // flags reuse histf's space (histf fully consumed before GRU launches)
  unsigned int* flags = (unsigned int*)(ws + 60817408ull);   // 4 grp x 16 x 64B = 4096

  gather_x<<<8192, 64, 0, stream>>>(loc, tim, eloc, etim, X);
  gemm_bf16<false><<<dim3(12, 64), 256, 0, stream>>>(X, W_ih, b_ih, gx, 8192, 1536, 320);
  hist_feat<<<16384, 64, 0, stream>>>(hloc, htim, huid, eloc, etim, euid, histf);
  gemm_bf16<true><<<dim3(4, 128), 256, 0, stream>>>(histf, W_attn, b_attn, histt, 16384, 512, 448);

  hipMemsetAsync(flags, 0, 4096, stream);   // stream-ordered: after gemm<true> consumed histf
  gru_persist<<<64, 128, 0, stream>>>(gx, W_hh, b_hh, lens, h_bf, lastb, flags);

  attn_ctx<<<64, 256, 0, stream>>>(histt, lastb, ctx);
  final_gemm<<<625, 256, 0, stream>>>(lastb, ctx, W_final, b_final, yv);
  broadcast_y<<<8192, 256, 0, stream>>>(yv, out);
}